// Round 4
// baseline (221.442 us; speedup 1.0000x reference)
//
#include <hip/hip_runtime.h>
#include <math.h>

#define THREADS 256

typedef __attribute__((ext_vector_type(8))) short bf16x8;
typedef __attribute__((ext_vector_type(4))) float f32x4;

// ws layout (bf16 elem offsets for weights; then f32 channel-last volume)
#define W0_OFF 0        // 256*32
#define W1_OFF 8192     // 256*256
#define W2_OFF 73728
#define W3_OFF 139264
#define WF_OFF 204800   // 4*256
#define WTS_BYTES 411648            // 205824 * 2, 16B-aligned

__device__ __forceinline__ ushort f2bf(float f) {
    union { float f; unsigned u; } v; v.f = f;
    unsigned r = v.u + 0x7FFFu + ((v.u >> 16) & 1u);
    return (ushort)(r >> 16);
}

__device__ __forceinline__ float fast_sigmoid(float x) {
    return 1.0f / (1.0f + __expf(-x));
}

// XOR-swizzled element offset into a [64][256] ushort buffer (512B rows).
__device__ __forceinline__ int swz(int row, int col) {
    const int chunk = (col >> 3) ^ (row & 7);
    return row * 256 + chunk * 8 + (col & 7);
}

// ---------------- prep kernels ----------------
__global__ void cvt_bf16(const float* __restrict__ src, ushort* __restrict__ dst, int n) {
    int i = blockIdx.x * 256 + threadIdx.x;
    if (i < n) dst[i] = f2bf(src[i]);
}

// vol [B][32][32768] f32 -> dst [B*32768][32] f32 (channel-last)
__global__ void vol_chlast(const float* __restrict__ vol, float* __restrict__ dst, int nvox) {
    int v = blockIdx.x * 256 + threadIdx.x;
    if (v >= nvox) return;
    const int b = v >> 15, idx = v & 32767;
    const float* s = vol + (size_t)b * 32 * 32768 + idx;
    float* d = dst + (size_t)v * 32;
#pragma unroll
    for (int c = 0; c < 32; ++c) d[c] = s[(size_t)c * 32768];
}

// ---------------- main fused kernel ----------------
// LDS (ushort): S[64][40]=2560, A0[64][256]=16384, A1[64][256]=16384
// total = 35328 ushort = 70656 B  -> 2 blocks/CU
extern __shared__ ushort ldsu[];

// One 256->64(per wave) dense layer + sin, weights ALREADY in registers
// (wf[8][4]). While consuming wf[ks][*], overwrite it with the NEXT layer's
// fragment (register-rotating prefetch) so the next layer starts with its
// weights resident / in flight.
__device__ __forceinline__ void layer256(const ushort* __restrict__ in,
                                         ushort* __restrict__ outb,
                                         bf16x8 (&wf)[8][4],
                                         const ushort* __restrict__ Wnext,
                                         bool prefetch,
                                         const float* __restrict__ bias,
                                         int nbase, int lr, int lc) {
    f32x4 acc[4][4];
#pragma unroll
    for (int nt = 0; nt < 4; ++nt) {
        const f32x4 bv = *(const f32x4*)(bias + nbase + nt * 16 + lc * 4);
#pragma unroll
        for (int ptt = 0; ptt < 4; ++ptt) acc[ptt][nt] = bv;
    }

#pragma unroll
    for (int ks = 0; ks < 8; ++ks) {
        const int kb = ks * 32 + lc * 8;
        bf16x8 af[4];
#pragma unroll
        for (int ptt = 0; ptt < 4; ++ptt)
            af[ptt] = *(const bf16x8*)(in + swz(ptt * 16 + lr, kb));
#pragma unroll
        for (int ptt = 0; ptt < 4; ++ptt)
#pragma unroll
            for (int nt = 0; nt < 4; ++nt)
                acc[ptt][nt] = __builtin_amdgcn_mfma_f32_16x16x32_bf16(wf[ks][nt], af[ptt], acc[ptt][nt], 0, 0, 0);
        if (prefetch) {
#pragma unroll
            for (int nt = 0; nt < 4; ++nt)
                wf[ks][nt] = *(const bf16x8*)(Wnext + (size_t)(nbase + nt * 16 + lr) * 256 + kb);
        }
    }

#pragma unroll
    for (int ptt = 0; ptt < 4; ++ptt) {
        const int row = ptt * 16 + lr;
#pragma unroll
        for (int nt = 0; nt < 4; ++nt) {
            const int n0 = nbase + nt * 16 + lc * 4;
            ushort4 o;
            o.x = f2bf(__sinf(acc[ptt][nt][0]));
            o.y = f2bf(__sinf(acc[ptt][nt][1]));
            o.z = f2bf(__sinf(acc[ptt][nt][2]));
            o.w = f2bf(__sinf(acc[ptt][nt][3]));
            *(ushort4*)(outb + swz(row, n0)) = o;
        }
    }
}

__global__ __launch_bounds__(THREADS, 2)
void siren_mfma(const float* __restrict__ points,
                const float* __restrict__ vol,
                const float* __restrict__ b0, const float* __restrict__ b1,
                const float* __restrict__ b2, const float* __restrict__ b3,
                const float* __restrict__ bfin,
                const ushort* __restrict__ Wb,
                const float* __restrict__ volcl, int use_cl,
                float* __restrict__ out, long long total, int N) {
    ushort* S  = ldsu;            // [64][40]
    ushort* A0 = ldsu + 2560;     // [64][256] swizzled
    ushort* A1 = A0 + 16384;

    const int tid = (int)threadIdx.x;
    const int w = tid >> 6;       // wave id (0..3) -> neuron group
    const int lane = tid & 63;
    const int lr = lane & 15;
    const int lc = lane >> 4;
    const int nbase = w * 64;

    const long long base = (long long)blockIdx.x * 64;

    // ---- up-front weight loads: W0 fragment + full W1 fragment ----
    // Issued before sampling so the gather latency covers them.
    bf16x8 w0f[4];
#pragma unroll
    for (int nt = 0; nt < 4; ++nt)
        w0f[nt] = *(const bf16x8*)(Wb + W0_OFF + (size_t)(nbase + nt * 16 + lr) * 32 + lc * 8);
    bf16x8 wf[8][4];
#pragma unroll
    for (int ks = 0; ks < 8; ++ks)
#pragma unroll
        for (int nt = 0; nt < 4; ++nt)
            wf[ks][nt] = *(const bf16x8*)(Wb + W1_OFF + (size_t)(nbase + nt * 16 + lr) * 256 + ks * 32 + lc * 8);

    // ---- trilinear border sample: thread -> point tid&63, channels (tid>>6)*8..+7
    {
        const int p = tid & 63;
        const int cg = tid >> 6;  // 0..3, 8 channels each
        const long long gidx = base + p;
        const long long gp = gidx < total ? gidx : total - 1;
        const int bi = (int)(gp / N);
        const float* pp = points + gp * 3;
        const float sc = 1.0f / 0.6f;
        const float ix = (pp[0] * sc + 1.0f) * 16.0f - 0.5f;
        const float iy = (pp[1] * sc + 1.0f) * 16.0f - 0.5f;
        const float iz = (pp[2] * sc + 1.0f) * 16.0f - 0.5f;
        const float fx = floorf(ix), fy = floorf(iy), fz = floorf(iz);
        const float wx = ix - fx, wy = iy - fy, wz = iz - fz;
        const int x0 = (int)fminf(fmaxf(fx, 0.0f), 31.0f);
        const int x1 = (int)fminf(fmaxf(fx + 1.0f, 0.0f), 31.0f);
        const int y0 = (int)fminf(fmaxf(fy, 0.0f), 31.0f);
        const int y1 = (int)fminf(fmaxf(fy + 1.0f, 0.0f), 31.0f);
        const int z0 = (int)fminf(fmaxf(fz, 0.0f), 31.0f);
        const int z1 = (int)fminf(fmaxf(fz + 1.0f, 0.0f), 31.0f);
        const int i000 = (z0 * 32 + y0) * 32 + x0, i001 = (z0 * 32 + y0) * 32 + x1;
        const int i010 = (z0 * 32 + y1) * 32 + x0, i011 = (z0 * 32 + y1) * 32 + x1;
        const int i100 = (z1 * 32 + y0) * 32 + x0, i101 = (z1 * 32 + y0) * 32 + x1;
        const int i110 = (z1 * 32 + y1) * 32 + x0, i111 = (z1 * 32 + y1) * 32 + x1;
        const float omx = 1.0f - wx, omy = 1.0f - wy, omz = 1.0f - wz;
        const float w000 = omz * omy * omx, w001 = omz * omy * wx;
        const float w010 = omz * wy * omx,  w011 = omz * wy * wx;
        const float w100 = wz * omy * omx,  w101 = wz * omy * wx;
        const float w110 = wz * wy * omx,   w111 = wz * wy * wx;

        f32x4 a[2];
        if (use_cl) {
            const float* vb = volcl + (size_t)bi * 32768 * 32 + cg * 8;
#pragma unroll
            for (int h = 0; h < 2; ++h) {
                const float* vh = vb + h * 4;
                a[h]  = w000 * *(const f32x4*)(vh + (size_t)i000 * 32);
                a[h] += w001 * *(const f32x4*)(vh + (size_t)i001 * 32);
                a[h] += w010 * *(const f32x4*)(vh + (size_t)i010 * 32);
                a[h] += w011 * *(const f32x4*)(vh + (size_t)i011 * 32);
                a[h] += w100 * *(const f32x4*)(vh + (size_t)i100 * 32);
                a[h] += w101 * *(const f32x4*)(vh + (size_t)i101 * 32);
                a[h] += w110 * *(const f32x4*)(vh + (size_t)i110 * 32);
                a[h] += w111 * *(const f32x4*)(vh + (size_t)i111 * 32);
            }
        } else {
            const float* vb = vol + ((size_t)bi * 32 + (size_t)cg * 8) * 32768;
#pragma unroll
            for (int c = 0; c < 8; ++c) {
                const float* vc = vb + (size_t)c * 32768;
                a[c >> 2][c & 3] =
                    vc[i000] * w000 + vc[i001] * w001 + vc[i010] * w010 + vc[i011] * w011 +
                    vc[i100] * w100 + vc[i101] * w101 + vc[i110] * w110 + vc[i111] * w111;
            }
        }
#pragma unroll
        for (int h = 0; h < 2; ++h) {
            ushort4 sv;
            sv.x = f2bf(a[h][0]); sv.y = f2bf(a[h][1]);
            sv.z = f2bf(a[h][2]); sv.w = f2bf(a[h][3]);
            *(ushort4*)(S + p * 40 + cg * 8 + h * 4) = sv;
        }
    }
    __syncthreads();

    // ---- layer 0: K=32 (weights in w0f) ----
    {
        f32x4 acc[4][4];
#pragma unroll
        for (int nt = 0; nt < 4; ++nt) {
            const f32x4 bv = *(const f32x4*)(b0 + nbase + nt * 16 + lc * 4);
#pragma unroll
            for (int ptt = 0; ptt < 4; ++ptt) acc[ptt][nt] = bv;
        }
#pragma unroll
        for (int ptt = 0; ptt < 4; ++ptt) {
            const bf16x8 af = *(const bf16x8*)(S + (ptt * 16 + lr) * 40 + lc * 8);
#pragma unroll
            for (int nt = 0; nt < 4; ++nt)
                acc[ptt][nt] = __builtin_amdgcn_mfma_f32_16x16x32_bf16(w0f[nt], af, acc[ptt][nt], 0, 0, 0);
        }
#pragma unroll
        for (int ptt = 0; ptt < 4; ++ptt) {
            const int row = ptt * 16 + lr;
#pragma unroll
            for (int nt = 0; nt < 4; ++nt) {
                const int n0 = nbase + nt * 16 + lc * 4;
                ushort4 o;
                o.x = f2bf(__sinf(acc[ptt][nt][0]));
                o.y = f2bf(__sinf(acc[ptt][nt][1]));
                o.z = f2bf(__sinf(acc[ptt][nt][2]));
                o.w = f2bf(__sinf(acc[ptt][nt][3]));
                *(ushort4*)(A0 + swz(row, n0)) = o;
            }
        }
    }
    __syncthreads();

    // steady-state: consume wf (=W_i), rotate-prefetch W_{i+1}
    layer256(A0, A1, wf, Wb + W2_OFF, true,  b1, nbase, lr, lc);
    __syncthreads();
    layer256(A1, A0, wf, Wb + W3_OFF, true,  b2, nbase, lr, lc);
    __syncthreads();
    layer256(A0, A1, wf, Wb + W3_OFF, false, b3, nbase, lr, lc);
    __syncthreads();

    // ---- final 256 -> 4: wave w covers points w*16..w*16+15 ----
    {
        f32x4 acc = {0.0f, 0.0f, 0.0f, 0.0f};
        const ushort* Wfb = Wb + WF_OFF;
        const int wr = lr < 4 ? lr : 3;   // rows >=4 produce unused garbage
#pragma unroll
        for (int ks = 0; ks < 8; ++ks) {
            const int kb = ks * 32 + lc * 8;
            const bf16x8 wfr = *(const bf16x8*)(Wfb + wr * 256 + kb);
            const bf16x8 af = *(const bf16x8*)(A1 + swz(w * 16 + lr, kb));
            acc = __builtin_amdgcn_mfma_f32_16x16x32_bf16(wfr, af, acc, 0, 0, 0);
        }
        if (lc == 0) {
            const long long oi = base + w * 16 + lr;
            if (oi < total) {
                float4 o;
                o.x = fast_sigmoid(acc[0] + bfin[0]);
                o.y = fast_sigmoid(acc[1] + bfin[1]);
                o.z = fast_sigmoid(acc[2] + bfin[2]);
                o.w = acc[3] + bfin[3];
                *(float4*)(out + oi * 4) = o;
            }
        }
    }
}

extern "C" void kernel_launch(void* const* d_in, const int* in_sizes, int n_in,
                              void* d_out, int out_size, void* d_ws, size_t ws_size,
                              hipStream_t stream) {
    const float* points = (const float*)d_in[0];
    const float* vol    = (const float*)d_in[1];
    const float* W0 = (const float*)d_in[2];
    const float* b0 = (const float*)d_in[3];
    const float* W1 = (const float*)d_in[4];
    const float* b1 = (const float*)d_in[5];
    const float* W2 = (const float*)d_in[6];
    const float* b2 = (const float*)d_in[7];
    const float* W3 = (const float*)d_in[8];
    const float* b3 = (const float*)d_in[9];
    const float* Wf = (const float*)d_in[10];
    const float* bf = (const float*)d_in[11];

    const int B = in_sizes[1] / (32 * 32 * 32 * 32);
    const int N = in_sizes[0] / (3 * B);
    const long long total = (long long)B * N;
    const int tiles = (int)((total + 63) / 64);

    ushort* Wb = (ushort*)d_ws;
    cvt_bf16<<<(8192 + 255) / 256, 256, 0, stream>>>(W0, Wb + W0_OFF, 8192);
    cvt_bf16<<<(65536 + 255) / 256, 256, 0, stream>>>(W1, Wb + W1_OFF, 65536);
    cvt_bf16<<<(65536 + 255) / 256, 256, 0, stream>>>(W2, Wb + W2_OFF, 65536);
    cvt_bf16<<<(65536 + 255) / 256, 256, 0, stream>>>(W3, Wb + W3_OFF, 65536);
    cvt_bf16<<<(1024 + 255) / 256, 256, 0, stream>>>(Wf, Wb + WF_OFF, 1024);

    const int use_cl = (ws_size >= (size_t)WTS_BYTES + (size_t)B * 32768 * 32 * 4) ? 1 : 0;
    float* volcl = (float*)((char*)d_ws + WTS_BYTES);
    if (use_cl) {
        const int nvox = B * 32768;
        vol_chlast<<<(nvox + 255) / 256, 256, 0, stream>>>(vol, volcl, nvox);
    }

    const size_t shmem = (size_t)(2560 + 2 * 16384) * sizeof(ushort);  // 70656 B
    hipFuncSetAttribute((const void*)siren_mfma,
                        hipFuncAttributeMaxDynamicSharedMemorySize, (int)shmem);

    siren_mfma<<<tiles, THREADS, shmem, stream>>>(
        points, vol, b0, b1, b2, b3, bf, Wb, volcl, use_cl,
        (float*)d_out, total, N);
}

// Round 5
// 121.010 us; speedup vs baseline: 1.8300x; 1.8300x over previous
//
#include <hip/hip_runtime.h>
#include <math.h>

#define THREADS 512

typedef __attribute__((ext_vector_type(8))) short bf16x8;
typedef __attribute__((ext_vector_type(4))) float f32x4;

// ---------------------------------------------------------------------------
// ws layout: [frag-major weight stream: 14 chunks x 32KB = 458752 B][volcl f32]
// Frag stream (1KB frags, 448 total):
//   f 0..15   : L0 (W0 256x32), frag nt=f            (no sigma)
//   f 16..31  : zero pad
//   f 32..159 : W1, q=f-32,  ks=q>>4, nt=q&15, cols sigma-permuted
//   f 160..287: W2
//   f 288..415: W3
//   f 416..423: Wf (4x256), rows>=4 zeroed, cols sigma-permuted
//   f 424..447: zero pad
#define STREAM_USHORT 229376
#define STREAM_BYTES  458752

__device__ __host__ __forceinline__ int sigma_k(int k) {
    // bits [b7 b6 b5 | b4 b3 | b2 b1 | b0] -> [b7 b6 b5 | b2 | b4 b3 | b1 | b0]
    return (k & 0xE1) | ((k & 0x04) << 2) | ((k & 0x18) >> 1) | (k & 0x02);
}

__device__ __forceinline__ ushort f2bf(float f) {
    union { float f; unsigned u; } v; v.f = f;
    unsigned r = v.u + 0x7FFFu + ((v.u >> 16) & 1u);
    return (ushort)(r >> 16);
}

__device__ __forceinline__ float fast_sigmoid(float x) {
    return 1.0f / (1.0f + __expf(-x));
}

__device__ __forceinline__ unsigned cvt_pk_bf16(float lo, float hi) {
    unsigned d;
    asm("v_cvt_pk_bf16_f32 %0, %1, %2" : "=v"(d) : "v"(lo), "v"(hi));
    return d;
}

// ---------------- prep kernels ----------------
// one thread = one (frag, lane): writes 8 bf16 (16B)
__global__ void build_frags(const float* __restrict__ W0,
                            const float* __restrict__ W1,
                            const float* __restrict__ W2,
                            const float* __restrict__ W3,
                            const float* __restrict__ Wf,
                            ushort* __restrict__ stream) {
    const int gid = blockIdx.x * 256 + threadIdx.x;   // 0 .. 28671
    const int f = gid >> 6;
    const int lane = gid & 63;
    const int p16 = lane & 15, g = lane >> 4;
    ushort* dst = stream + (size_t)f * 512 + lane * 8;

    if (f < 16) {                       // L0: W0[nt*16+p16][8g+i]
        const float* row = W0 + (size_t)(f * 16 + p16) * 32;
#pragma unroll
        for (int i = 0; i < 8; ++i) dst[i] = f2bf(row[8 * g + i]);
    } else if (f < 32) {
#pragma unroll
        for (int i = 0; i < 8; ++i) dst[i] = 0;
    } else if (f < 416) {
        const int h = (f - 32) >> 7;    // 0,1,2 -> W1,W2,W3
        const int q = (f - 32) & 127;
        const int ks = q >> 4, nt = q & 15;
        const float* W = (h == 0) ? W1 : (h == 1) ? W2 : W3;
        const float* row = W + (size_t)(nt * 16 + p16) * 256;
#pragma unroll
        for (int i = 0; i < 8; ++i) dst[i] = f2bf(row[sigma_k(32 * ks + 8 * g + i)]);
    } else if (f < 424) {               // Wf
        const int ks = f - 416;
        if (p16 < 4) {
            const float* row = Wf + (size_t)p16 * 256;
#pragma unroll
            for (int i = 0; i < 8; ++i) dst[i] = f2bf(row[sigma_k(32 * ks + 8 * g + i)]);
        } else {
#pragma unroll
            for (int i = 0; i < 8; ++i) dst[i] = 0;
        }
    } else {
#pragma unroll
        for (int i = 0; i < 8; ++i) dst[i] = 0;
    }
}

// vol [B][32][32768] f32 -> dst [B*32768][32] f32 (channel-last)
__global__ void vol_chlast(const float* __restrict__ vol, float* __restrict__ dst, int nvox) {
    int v = blockIdx.x * 256 + threadIdx.x;
    if (v >= nvox) return;
    const int b = v >> 15, idx = v & 32767;
    const float* s = vol + (size_t)b * 32 * 32768 + idx;
    float* d = dst + (size_t)v * 32;
#pragma unroll
    for (int c = 0; c < 32; ++c) d[c] = s[(size_t)c * 32768];
}

// ---------------- main fused kernel ----------------
#define MF(a, b, c) __builtin_amdgcn_mfma_f32_16x16x32_bf16((a), (b), (c), 0, 0, 0)

__global__ __launch_bounds__(THREADS, 2)
void siren_pl(const float* __restrict__ points,
              const float* __restrict__ vol,
              const float* __restrict__ b0, const float* __restrict__ b1,
              const float* __restrict__ b2, const float* __restrict__ b3,
              const float* __restrict__ bfin,
              const ushort* __restrict__ Wstream,
              const float* __restrict__ volcl, int use_cl,
              float* __restrict__ out, long long total, int N) {
    __shared__ ushort ring[2][16384];   // 2 x 32KB

    const int tid = (int)threadIdx.x;
    const int w = tid >> 6;             // wave 0..7
    const int lane = tid & 63;
    const int p16 = lane & 15;
    const int g = lane >> 4;

    const long long base = (long long)blockIdx.x * 256;

    // ---- stage chunks 0,1 (in flight under the sampling gathers) ----
    auto stage = [&](int c) {
        if (c >= 14) return;
        const ushort* src = Wstream + (size_t)c * 16384;
        ushort* dstbase = &ring[c & 1][0];
#pragma unroll
        for (int q = 0; q < 4; ++q) {
            const int off = (q * 8 + w) * 512;   // elements; wave-uniform
            __builtin_amdgcn_global_load_lds(
                (const __attribute__((address_space(1))) unsigned int*)(src + off + lane * 8),
                (__attribute__((address_space(3))) unsigned int*)(dstbase + off),
                16, 0, 0);
        }
    };
    stage(0);
    stage(1);

    // ---- sample 2 points per lane: channels 8g..8g+7 ----
    bf16x8 af0[2];
    {
#pragma unroll
        for (int ptt = 0; ptt < 2; ++ptt) {
            const long long gidx = base + w * 32 + ptt * 16 + p16;
            const long long gp = gidx < total ? gidx : total - 1;
            const int bi = (int)(gp / N);
            const float* pp = points + gp * 3;
            const float sc = 1.0f / 0.6f;
            const float ix = (pp[0] * sc + 1.0f) * 16.0f - 0.5f;
            const float iy = (pp[1] * sc + 1.0f) * 16.0f - 0.5f;
            const float iz = (pp[2] * sc + 1.0f) * 16.0f - 0.5f;
            const float fx = floorf(ix), fy = floorf(iy), fz = floorf(iz);
            const float wx = ix - fx, wy = iy - fy, wz = iz - fz;
            const int x0 = (int)fminf(fmaxf(fx, 0.0f), 31.0f);
            const int x1 = (int)fminf(fmaxf(fx + 1.0f, 0.0f), 31.0f);
            const int y0 = (int)fminf(fmaxf(fy, 0.0f), 31.0f);
            const int y1 = (int)fminf(fmaxf(fy + 1.0f, 0.0f), 31.0f);
            const int z0 = (int)fminf(fmaxf(fz, 0.0f), 31.0f);
            const int z1 = (int)fminf(fmaxf(fz + 1.0f, 0.0f), 31.0f);
            const int i000 = (z0 * 32 + y0) * 32 + x0, i001 = (z0 * 32 + y0) * 32 + x1;
            const int i010 = (z0 * 32 + y1) * 32 + x0, i011 = (z0 * 32 + y1) * 32 + x1;
            const int i100 = (z1 * 32 + y0) * 32 + x0, i101 = (z1 * 32 + y0) * 32 + x1;
            const int i110 = (z1 * 32 + y1) * 32 + x0, i111 = (z1 * 32 + y1) * 32 + x1;
            const float omx = 1.0f - wx, omy = 1.0f - wy, omz = 1.0f - wz;
            const float w000 = omz * omy * omx, w001 = omz * omy * wx;
            const float w010 = omz * wy * omx,  w011 = omz * wy * wx;
            const float w100 = wz * omy * omx,  w101 = wz * omy * wx;
            const float w110 = wz * wy * omx,   w111 = wz * wy * wx;

            f32x4 a[2];
            if (use_cl) {
                const float* vb = volcl + (size_t)bi * 32768 * 32 + g * 8;
#pragma unroll
                for (int h = 0; h < 2; ++h) {
                    const float* vh = vb + h * 4;
                    a[h]  = w000 * *(const f32x4*)(vh + (size_t)i000 * 32);
                    a[h] += w001 * *(const f32x4*)(vh + (size_t)i001 * 32);
                    a[h] += w010 * *(const f32x4*)(vh + (size_t)i010 * 32);
                    a[h] += w011 * *(const f32x4*)(vh + (size_t)i011 * 32);
                    a[h] += w100 * *(const f32x4*)(vh + (size_t)i100 * 32);
                    a[h] += w101 * *(const f32x4*)(vh + (size_t)i101 * 32);
                    a[h] += w110 * *(const f32x4*)(vh + (size_t)i110 * 32);
                    a[h] += w111 * *(const f32x4*)(vh + (size_t)i111 * 32);
                }
            } else {
                const float* vb = vol + ((size_t)bi * 32 + (size_t)g * 8) * 32768;
#pragma unroll
                for (int c = 0; c < 8; ++c) {
                    const float* vc = vb + (size_t)c * 32768;
                    a[c >> 2][c & 3] =
                        vc[i000] * w000 + vc[i001] * w001 + vc[i010] * w010 + vc[i011] * w011 +
                        vc[i100] * w100 + vc[i101] * w101 + vc[i110] * w110 + vc[i111] * w111;
                }
            }
            union { bf16x8 v; unsigned u[4]; } pk;
            pk.u[0] = cvt_pk_bf16(a[0][0], a[0][1]);
            pk.u[1] = cvt_pk_bf16(a[0][2], a[0][3]);
            pk.u[2] = cvt_pk_bf16(a[1][0], a[1][1]);
            pk.u[3] = cvt_pk_bf16(a[1][2], a[1][3]);
            af0[ptt] = pk.v;
        }
    }

    f32x4 acc[2][16];
    bf16x8 bfr[2][8];

    auto frag_at = [&](int slot, int idx) -> bf16x8 {
        return *(const bf16x8*)&ring[slot][idx * 512 + lane * 8];
    };
    auto init_acc = [&](const float* __restrict__ b) {
#pragma unroll
        for (int nt = 0; nt < 16; ++nt) {
            const f32x4 bv = *(const f32x4*)&b[nt * 16 + 4 * g];
            acc[0][nt] = bv; acc[1][nt] = bv;
        }
    };
    // pack: frag[ks].dword[j] = pk(sin(acc[2ks+(j>>1)][2(j&1)]), sin(acc[..][2(j&1)+1]))
    auto pack_layer = [&]() {
#pragma unroll
        for (int ptt = 0; ptt < 2; ++ptt)
#pragma unroll
            for (int ks = 0; ks < 8; ++ks) {
                union { bf16x8 v; unsigned u[4]; } pk;
#pragma unroll
                for (int j = 0; j < 4; ++j) {
                    const int t = 2 * ks + (j >> 1);
                    const int r = 2 * (j & 1);
                    pk.u[j] = cvt_pk_bf16(__sinf(acc[ptt][t][r]), __sinf(acc[ptt][t][r + 1]));
                }
                bfr[ptt][ks] = pk.v;
            }
    };

    __syncthreads();                    // chunks 0,1 staged

    // ---- L0 (chunk 0) ----
    init_acc(b0);
#pragma unroll
    for (int nt = 0; nt < 16; ++nt) {
        const bf16x8 wfr = frag_at(0, nt);
        acc[0][nt] = MF(wfr, af0[0], acc[0][nt]);
        acc[1][nt] = MF(wfr, af0[1], acc[1][nt]);
    }
    __syncthreads();
    stage(2);
    pack_layer();
    init_acc(b1);

#define HIDDEN_CHUNK(c, ksbase)                                        \
    do {                                                               \
        _Pragma("unroll")                                              \
        for (int ks2 = 0; ks2 < 2; ++ks2) {                            \
            _Pragma("unroll")                                          \
            for (int nt = 0; nt < 16; ++nt) {                          \
                const bf16x8 wfr = frag_at((c) & 1, ks2 * 16 + nt);    \
                acc[0][nt] = MF(wfr, bfr[0][(ksbase) + ks2], acc[0][nt]); \
                acc[1][nt] = MF(wfr, bfr[1][(ksbase) + ks2], acc[1][nt]); \
            }                                                          \
        }                                                              \
        __syncthreads();                                               \
        stage((c) + 2);                                                \
    } while (0)

    // ---- L1: chunks 1..4 ----
    HIDDEN_CHUNK(1, 0); HIDDEN_CHUNK(2, 2); HIDDEN_CHUNK(3, 4); HIDDEN_CHUNK(4, 6);
    pack_layer(); init_acc(b2);
    // ---- L2: chunks 5..8 ----
    HIDDEN_CHUNK(5, 0); HIDDEN_CHUNK(6, 2); HIDDEN_CHUNK(7, 4); HIDDEN_CHUNK(8, 6);
    pack_layer(); init_acc(b3);
    // ---- L3: chunks 9..12 ----
    HIDDEN_CHUNK(9, 0); HIDDEN_CHUNK(10, 2); HIDDEN_CHUNK(11, 4); HIDDEN_CHUNK(12, 6);
    pack_layer();

    // ---- final (chunk 13): Wf, rows 0..3 ----
    {
        f32x4 fo[2] = {{0, 0, 0, 0}, {0, 0, 0, 0}};
#pragma unroll
        for (int ks = 0; ks < 8; ++ks) {
            const bf16x8 wfr = frag_at(1, ks);
            fo[0] = MF(wfr, bfr[0][ks], fo[0]);
            fo[1] = MF(wfr, bfr[1][ks], fo[1]);
        }
        if (g == 0) {
#pragma unroll
            for (int ptt = 0; ptt < 2; ++ptt) {
                const long long oi = base + w * 32 + ptt * 16 + p16;
                if (oi < total) {
                    float4 o;
                    o.x = fast_sigmoid(fo[ptt][0] + bfin[0]);
                    o.y = fast_sigmoid(fo[ptt][1] + bfin[1]);
                    o.z = fast_sigmoid(fo[ptt][2] + bfin[2]);
                    o.w = fo[ptt][3] + bfin[3];
                    *(float4*)(out + oi * 4) = o;
                }
            }
        }
    }
}

extern "C" void kernel_launch(void* const* d_in, const int* in_sizes, int n_in,
                              void* d_out, int out_size, void* d_ws, size_t ws_size,
                              hipStream_t stream) {
    const float* points = (const float*)d_in[0];
    const float* vol    = (const float*)d_in[1];
    const float* W0 = (const float*)d_in[2];
    const float* b0 = (const float*)d_in[3];
    const float* W1 = (const float*)d_in[4];
    const float* b1 = (const float*)d_in[5];
    const float* W2 = (const float*)d_in[6];
    const float* b2 = (const float*)d_in[7];
    const float* W3 = (const float*)d_in[8];
    const float* b3 = (const float*)d_in[9];
    const float* Wf = (const float*)d_in[10];
    const float* bf = (const float*)d_in[11];

    const int B = in_sizes[1] / (32 * 32 * 32 * 32);
    const int N = in_sizes[0] / (3 * B);
    const long long total = (long long)B * N;
    const int tiles = (int)((total + 255) / 256);

    ushort* Wstream = (ushort*)d_ws;
    build_frags<<<112, 256, 0, stream>>>(W0, W1, W2, W3, Wf, Wstream);

    const int use_cl = (ws_size >= (size_t)STREAM_BYTES + (size_t)B * 32768 * 32 * 4) ? 1 : 0;
    float* volcl = (float*)((char*)d_ws + STREAM_BYTES);
    if (use_cl) {
        const int nvox = B * 32768;
        vol_chlast<<<(nvox + 255) / 256, 256, 0, stream>>>(vol, volcl, nvox);
    }

    siren_pl<<<tiles, THREADS, 0, stream>>>(
        points, vol, b0, b1, b2, b3, bf, Wstream, volcl, use_cl,
        (float*)d_out, total, N);
}

// Round 6
// 111.389 us; speedup vs baseline: 1.9880x; 1.0864x over previous
//
#include <hip/hip_runtime.h>
#include <math.h>

#define THREADS 512

typedef __attribute__((ext_vector_type(8))) short bf16x8;
typedef __attribute__((ext_vector_type(4))) float f32x4;

// ---------------------------------------------------------------------------
// ws layout: [frag-major weight stream: 14 chunks x 32KB = 458752 B][volcl f32]
// Frag = 1KB (16 neurons x 32 k, 512 bf16). 448 frags total.
//   chunk 0      : L0 (W0 256x32): frags nt=0..15, then 16 zero frags
//   chunks 1+4h..4+4h (h=0..2 -> W1..W3): per layer 128 frags in sub-chunks
//       A: nt 0..7  x ks 0..3      B: nt 8..15 x ks 0..3
//       C: nt 0..7  x ks 4..7      D: nt 8..15 x ks 4..7
//     within sub-chunk: idx = ksl*8 + ntl
//   chunk 13     : Wf frags ks=0..7 (rows>=4 zero), then 24 zero frags
#define STREAM_BYTES  458752

__device__ __host__ __forceinline__ int sigma_k(int k) {
    // bits [b7 b6 b5 | b4 b3 | b2 b1 | b0] -> [b7 b6 b5 | b2 | b4 b3 | b1 | b0]
    return (k & 0xE1) | ((k & 0x04) << 2) | ((k & 0x18) >> 1) | (k & 0x02);
}

__device__ __forceinline__ ushort f2bf(float f) {
    union { float f; unsigned u; } v; v.f = f;
    unsigned r = v.u + 0x7FFFu + ((v.u >> 16) & 1u);
    return (ushort)(r >> 16);
}

__device__ __forceinline__ float fast_sigmoid(float x) {
    return 1.0f / (1.0f + __expf(-x));
}

__device__ __forceinline__ unsigned cvt_pk_bf16(float lo, float hi) {
    unsigned d;
    asm("v_cvt_pk_bf16_f32 %0, %1, %2" : "=v"(d) : "v"(lo), "v"(hi));
    return d;
}

// ---------------- prep kernels ----------------
__global__ void build_frags(const float* __restrict__ W0,
                            const float* __restrict__ W1,
                            const float* __restrict__ W2,
                            const float* __restrict__ W3,
                            const float* __restrict__ Wf,
                            ushort* __restrict__ stream) {
    const int gid = blockIdx.x * 256 + threadIdx.x;   // 0 .. 28671
    const int f = gid >> 6;
    const int lane = gid & 63;
    const int p16 = lane & 15, g = lane >> 4;
    ushort* dst = stream + (size_t)f * 512 + lane * 8;

    if (f < 16) {                       // L0: W0[f*16+p16][8g+i]
        const float* row = W0 + (size_t)(f * 16 + p16) * 32;
#pragma unroll
        for (int i = 0; i < 8; ++i) dst[i] = f2bf(row[8 * g + i]);
    } else if (f < 32) {
#pragma unroll
        for (int i = 0; i < 8; ++i) dst[i] = 0;
    } else if (f < 416) {
        const int t = f - 32;
        const int h = t >> 7;           // 0,1,2 -> W1,W2,W3
        const int q = (t >> 5) & 3;     // sub-chunk A,B,C,D
        const int ksl = (t >> 3) & 3;
        const int ntl = t & 7;
        const int nt = (q & 1) * 8 + ntl;
        const int ks = (q >> 1) * 4 + ksl;
        const float* W = (h == 0) ? W1 : (h == 1) ? W2 : W3;
        const float* row = W + (size_t)(nt * 16 + p16) * 256;
#pragma unroll
        for (int i = 0; i < 8; ++i) dst[i] = f2bf(row[sigma_k(32 * ks + 8 * g + i)]);
    } else if (f < 424) {               // Wf
        const int ks = f - 416;
        if (p16 < 4) {
            const float* row = Wf + (size_t)p16 * 256;
#pragma unroll
            for (int i = 0; i < 8; ++i) dst[i] = f2bf(row[sigma_k(32 * ks + 8 * g + i)]);
        } else {
#pragma unroll
            for (int i = 0; i < 8; ++i) dst[i] = 0;
        }
    } else {
#pragma unroll
        for (int i = 0; i < 8; ++i) dst[i] = 0;
    }
}

// vol [B][32][32768] f32 -> dst [B*32768][32] f32 (channel-last)
__global__ void vol_chlast(const float* __restrict__ vol, float* __restrict__ dst, int nvox) {
    int v = blockIdx.x * 256 + threadIdx.x;
    if (v >= nvox) return;
    const int b = v >> 15, idx = v & 32767;
    const float* s = vol + (size_t)b * 32 * 32768 + idx;
    float* d = dst + (size_t)v * 32;
#pragma unroll
    for (int c = 0; c < 32; ++c) d[c] = s[(size_t)c * 32768];
}

// ---------------- main fused kernel ----------------
#define MF(a, b, c) __builtin_amdgcn_mfma_f32_16x16x32_bf16((a), (b), (c), 0, 0, 0)

__global__ __launch_bounds__(THREADS, 2)
void siren_pl(const float* __restrict__ points,
              const float* __restrict__ vol,
              const float* __restrict__ b0, const float* __restrict__ b1,
              const float* __restrict__ b2, const float* __restrict__ b3,
              const float* __restrict__ bfin,
              const ushort* __restrict__ Wstream,
              const float* __restrict__ volcl, int use_cl,
              float* __restrict__ out, long long total, int N) {
    __shared__ ushort ring[2][16384];   // 2 x 32KB

    const int tid = (int)threadIdx.x;
    const int w = tid >> 6;             // wave 0..7
    const int lane = tid & 63;
    const int p16 = lane & 15;
    const int g = lane >> 4;

    const long long base = (long long)blockIdx.x * 256;

    auto stage = [&](int c) {
        if (c >= 14) return;
        const ushort* src = Wstream + (size_t)c * 16384;
        ushort* dstbase = &ring[c & 1][0];
#pragma unroll
        for (int q = 0; q < 4; ++q) {
            const int off = (q * 8 + w) * 512;   // elements; wave-uniform
            __builtin_amdgcn_global_load_lds(
                (const __attribute__((address_space(1))) unsigned int*)(src + off + lane * 8),
                (__attribute__((address_space(3))) unsigned int*)(dstbase + off),
                16, 0, 0);
        }
    };
    stage(0);
    stage(1);

    // ---- sample 2 points per lane: channels 8g..8g+7 ----
    bf16x8 af0[2];
    {
#pragma unroll
        for (int ptt = 0; ptt < 2; ++ptt) {
            const long long gidx = base + w * 32 + ptt * 16 + p16;
            const long long gp = gidx < total ? gidx : total - 1;
            const int bi = (int)(gp / N);
            const float* pp = points + gp * 3;
            const float sc = 1.0f / 0.6f;
            const float ix = (pp[0] * sc + 1.0f) * 16.0f - 0.5f;
            const float iy = (pp[1] * sc + 1.0f) * 16.0f - 0.5f;
            const float iz = (pp[2] * sc + 1.0f) * 16.0f - 0.5f;
            const float fx = floorf(ix), fy = floorf(iy), fz = floorf(iz);
            const float wx = ix - fx, wy = iy - fy, wz = iz - fz;
            const int x0 = (int)fminf(fmaxf(fx, 0.0f), 31.0f);
            const int x1 = (int)fminf(fmaxf(fx + 1.0f, 0.0f), 31.0f);
            const int y0 = (int)fminf(fmaxf(fy, 0.0f), 31.0f);
            const int y1 = (int)fminf(fmaxf(fy + 1.0f, 0.0f), 31.0f);
            const int z0 = (int)fminf(fmaxf(fz, 0.0f), 31.0f);
            const int z1 = (int)fminf(fmaxf(fz + 1.0f, 0.0f), 31.0f);
            const int i000 = (z0 * 32 + y0) * 32 + x0, i001 = (z0 * 32 + y0) * 32 + x1;
            const int i010 = (z0 * 32 + y1) * 32 + x0, i011 = (z0 * 32 + y1) * 32 + x1;
            const int i100 = (z1 * 32 + y0) * 32 + x0, i101 = (z1 * 32 + y0) * 32 + x1;
            const int i110 = (z1 * 32 + y1) * 32 + x0, i111 = (z1 * 32 + y1) * 32 + x1;
            const float omx = 1.0f - wx, omy = 1.0f - wy, omz = 1.0f - wz;
            const float w000 = omz * omy * omx, w001 = omz * omy * wx;
            const float w010 = omz * wy * omx,  w011 = omz * wy * wx;
            const float w100 = wz * omy * omx,  w101 = wz * omy * wx;
            const float w110 = wz * wy * omx,   w111 = wz * wy * wx;

            f32x4 a[2];
            if (use_cl) {
                const float* vb = volcl + (size_t)bi * 32768 * 32 + g * 8;
#pragma unroll
                for (int h = 0; h < 2; ++h) {
                    const float* vh = vb + h * 4;
                    a[h]  = w000 * *(const f32x4*)(vh + (size_t)i000 * 32);
                    a[h] += w001 * *(const f32x4*)(vh + (size_t)i001 * 32);
                    a[h] += w010 * *(const f32x4*)(vh + (size_t)i010 * 32);
                    a[h] += w011 * *(const f32x4*)(vh + (size_t)i011 * 32);
                    a[h] += w100 * *(const f32x4*)(vh + (size_t)i100 * 32);
                    a[h] += w101 * *(const f32x4*)(vh + (size_t)i101 * 32);
                    a[h] += w110 * *(const f32x4*)(vh + (size_t)i110 * 32);
                    a[h] += w111 * *(const f32x4*)(vh + (size_t)i111 * 32);
                }
            } else {
                const float* vb = vol + ((size_t)bi * 32 + (size_t)g * 8) * 32768;
#pragma unroll
                for (int c = 0; c < 8; ++c) {
                    const float* vc = vb + (size_t)c * 32768;
                    a[c >> 2][c & 3] =
                        vc[i000] * w000 + vc[i001] * w001 + vc[i010] * w010 + vc[i011] * w011 +
                        vc[i100] * w100 + vc[i101] * w101 + vc[i110] * w110 + vc[i111] * w111;
                }
            }
            union { bf16x8 v; unsigned u[4]; } pk;
            pk.u[0] = cvt_pk_bf16(a[0][0], a[0][1]);
            pk.u[1] = cvt_pk_bf16(a[0][2], a[0][3]);
            pk.u[2] = cvt_pk_bf16(a[1][0], a[1][1]);
            pk.u[3] = cvt_pk_bf16(a[1][2], a[1][3]);
            af0[ptt] = pk.v;
        }
    }

    f32x4 accA[2][8];   // nt 0..7
    f32x4 accB[2][8];   // nt 8..15
    bf16x8 bfr[2][8];   // activations, frag ks=0..7

    auto frag_at = [&](int slot, int idx) -> bf16x8 {
        return *(const bf16x8*)&ring[slot][idx * 512 + lane * 8];
    };
    auto init_half = [&](f32x4 (&A)[2][8], const float* __restrict__ b, int ntbase) {
#pragma unroll
        for (int m = 0; m < 8; ++m) {
            const f32x4 bv = *(const f32x4*)&b[(ntbase + m) * 16 + 4 * g];
            A[0][m] = bv; A[1][m] = bv;
        }
    };
    // pack 8 acc tiles (one nt-half) into bfr[ksbase..ksbase+3]
    auto pack_half = [&](f32x4 (&A)[2][8], int ksbase) {
#pragma unroll
        for (int ptt = 0; ptt < 2; ++ptt)
#pragma unroll
            for (int ks2 = 0; ks2 < 4; ++ks2) {
                union { bf16x8 v; unsigned u[4]; } pk;
#pragma unroll
                for (int j = 0; j < 4; ++j) {
                    const int m = 2 * ks2 + (j >> 1);
                    const int r = 2 * (j & 1);
                    pk.u[j] = cvt_pk_bf16(__sinf(A[ptt][m][r]), __sinf(A[ptt][m][r + 1]));
                }
                bfr[ptt][ksbase + ks2] = pk.v;
            }
    };
    // one 32KB sub-chunk: 32 frags (ksl 0..3 x ntl 0..7) vs bfr[kh*4+ksl]
    auto chunk_mfma = [&](int slot, int kh, f32x4 (&A)[2][8]) {
        __builtin_amdgcn_s_setprio(1);
#pragma unroll
        for (int ksl = 0; ksl < 4; ++ksl) {
            const bf16x8 bA = bfr[0][kh * 4 + ksl];
            const bf16x8 bB = bfr[1][kh * 4 + ksl];
#pragma unroll
            for (int ntl = 0; ntl < 8; ++ntl) {
                const bf16x8 wfr = frag_at(slot, ksl * 8 + ntl);
                A[0][ntl] = MF(wfr, bA, A[0][ntl]);
                A[1][ntl] = MF(wfr, bB, A[1][ntl]);
            }
        }
        __builtin_amdgcn_s_setprio(0);
    };

    init_half(accA, b0, 0);
    init_half(accB, b0, 8);
    __syncthreads();                    // chunks 0,1 staged

    // ---- interval 0: L0 (chunk 0) ----
    __builtin_amdgcn_s_setprio(1);
#pragma unroll
    for (int ntl = 0; ntl < 8; ++ntl) {
        const bf16x8 wl = frag_at(0, ntl);
        const bf16x8 wh = frag_at(0, 8 + ntl);
        accA[0][ntl] = MF(wl, af0[0], accA[0][ntl]);
        accA[1][ntl] = MF(wl, af0[1], accA[1][ntl]);
        accB[0][ntl] = MF(wh, af0[0], accB[0][ntl]);
        accB[1][ntl] = MF(wh, af0[1], accB[1][ntl]);
    }
    __builtin_amdgcn_s_setprio(0);
    __syncthreads(); stage(2);

    // ---- interval 1 (c1 = L1.A) ----
    pack_half(accA, 0); init_half(accA, b1, 0);
    chunk_mfma(1, 0, accA);
    __syncthreads(); stage(3);
    // ---- interval 2 (c2 = L1.B) ----
    pack_half(accB, 4); init_half(accB, b1, 8);
    chunk_mfma(0, 0, accB);
    __syncthreads(); stage(4);
    // ---- interval 3 (c3 = L1.C) ----
    chunk_mfma(1, 1, accA);
    __syncthreads(); stage(5);
    // ---- interval 4 (c4 = L1.D) ----
    pack_half(accA, 0); init_half(accA, b2, 0);
    chunk_mfma(0, 1, accB);
    __syncthreads(); stage(6);
    // ---- interval 5 (c5 = L2.A) ----
    pack_half(accB, 4); init_half(accB, b2, 8);
    chunk_mfma(1, 0, accA);
    __syncthreads(); stage(7);
    // ---- interval 6 (c6 = L2.B) ----
    chunk_mfma(0, 0, accB);
    __syncthreads(); stage(8);
    // ---- interval 7 (c7 = L2.C) ----
    chunk_mfma(1, 1, accA);
    __syncthreads(); stage(9);
    // ---- interval 8 (c8 = L2.D) ----
    pack_half(accA, 0); init_half(accA, b3, 0);
    chunk_mfma(0, 1, accB);
    __syncthreads(); stage(10);
    // ---- interval 9 (c9 = L3.A) ----
    pack_half(accB, 4); init_half(accB, b3, 8);
    chunk_mfma(1, 0, accA);
    __syncthreads(); stage(11);
    // ---- interval 10 (c10 = L3.B) ----
    chunk_mfma(0, 0, accB);
    __syncthreads(); stage(12);
    // ---- interval 11 (c11 = L3.C) ----
    chunk_mfma(1, 1, accA);
    __syncthreads(); stage(13);
    // ---- interval 12 (c12 = L3.D) ----
    pack_half(accA, 0);
    chunk_mfma(0, 1, accB);
    __syncthreads();
    // ---- interval 13 (c13 = Wf) ----
    pack_half(accB, 4);
    {
        f32x4 fo[2] = {{0, 0, 0, 0}, {0, 0, 0, 0}};
#pragma unroll
        for (int ks = 0; ks < 8; ++ks) {
            const bf16x8 wfr = frag_at(1, ks);
            fo[0] = MF(wfr, bfr[0][ks], fo[0]);
            fo[1] = MF(wfr, bfr[1][ks], fo[1]);
        }
        if (g == 0) {
#pragma unroll
            for (int ptt = 0; ptt < 2; ++ptt) {
                const long long oi = base + w * 32 + ptt * 16 + p16;
                if (oi < total) {
                    float4 o;
                    o.x = fast_sigmoid(fo[ptt][0] + bfin[0]);
                    o.y = fast_sigmoid(fo[ptt][1] + bfin[1]);
                    o.z = fast_sigmoid(fo[ptt][2] + bfin[2]);
                    o.w = fo[ptt][3] + bfin[3];
                    *(float4*)(out + oi * 4) = o;
                }
            }
        }
    }
}

extern "C" void kernel_launch(void* const* d_in, const int* in_sizes, int n_in,
                              void* d_out, int out_size, void* d_ws, size_t ws_size,
                              hipStream_t stream) {
    const float* points = (const float*)d_in[0];
    const float* vol    = (const float*)d_in[1];
    const float* W0 = (const float*)d_in[2];
    const float* b0 = (const float*)d_in[3];
    const float* W1 = (const float*)d_in[4];
    const float* b1 = (const float*)d_in[5];
    const float* W2 = (const float*)d_in[6];
    const float* b2 = (const float*)d_in[7];
    const float* W3 = (const float*)d_in[8];
    const float* b3 = (const float*)d_in[9];
    const float* Wf = (const float*)d_in[10];
    const float* bf = (const float*)d_in[11];

    const int B = in_sizes[1] / (32 * 32 * 32 * 32);
    const int N = in_sizes[0] / (3 * B);
    const long long total = (long long)B * N;
    const int tiles = (int)((total + 255) / 256);

    ushort* Wstream = (ushort*)d_ws;
    build_frags<<<112, 256, 0, stream>>>(W0, W1, W2, W3, Wf, Wstream);

    const int use_cl = (ws_size >= (size_t)STREAM_BYTES + (size_t)B * 32768 * 32 * 4) ? 1 : 0;
    float* volcl = (float*)((char*)d_ws + STREAM_BYTES);
    if (use_cl) {
        const int nvox = B * 32768;
        vol_chlast<<<(nvox + 255) / 256, 256, 0, stream>>>(vol, volcl, nvox);
    }

    siren_pl<<<tiles, THREADS, 0, stream>>>(
        points, vol, b0, b1, b2, b3, bf, Wstream, volcl, use_cl,
        (float*)d_out, total, N);
}

// Round 7
// 107.692 us; speedup vs baseline: 2.0562x; 1.0343x over previous
//
#include <hip/hip_runtime.h>
#include <math.h>

#define THREADS 256   // 4 waves/block, 128 pts/block -> 2 blocks/CU co-resident

typedef __attribute__((ext_vector_type(8))) short bf16x8;
typedef __attribute__((ext_vector_type(4))) float f32x4;

// ---------------------------------------------------------------------------
// ws layout: [frag-major weight stream: 14 chunks x 32KB = 458752 B][volcl f32]
// Frag = 1KB (16 neurons x 32 k, 512 bf16). 448 frags total.
//   chunk 0      : L0 (W0 256x32): frags nt=0..15, then 16 zero frags
//   chunks 1+4h..4+4h (h=0..2 -> W1..W3): per layer 128 frags in sub-chunks
//       A: nt 0..7  x ks 0..3      B: nt 8..15 x ks 0..3
//       C: nt 0..7  x ks 4..7      D: nt 8..15 x ks 4..7
//     within sub-chunk: idx = ksl*8 + ntl
//   chunk 13     : Wf frags ks=0..7 (rows>=4 zero), then 24 zero frags
#define STREAM_BYTES  458752

__device__ __host__ __forceinline__ int sigma_k(int k) {
    // bits [b7 b6 b5 | b4 b3 | b2 b1 | b0] -> [b7 b6 b5 | b2 | b4 b3 | b1 | b0]
    return (k & 0xE1) | ((k & 0x04) << 2) | ((k & 0x18) >> 1) | (k & 0x02);
}

__device__ __forceinline__ ushort f2bf(float f) {
    union { float f; unsigned u; } v; v.f = f;
    unsigned r = v.u + 0x7FFFu + ((v.u >> 16) & 1u);
    return (ushort)(r >> 16);
}

__device__ __forceinline__ float fast_sigmoid(float x) {
    return 1.0f / (1.0f + __expf(-x));
}

__device__ __forceinline__ unsigned cvt_pk_bf16(float lo, float hi) {
    unsigned d;
    asm("v_cvt_pk_bf16_f32 %0, %1, %2" : "=v"(d) : "v"(lo), "v"(hi));
    return d;
}

// ---------------- prep kernels ----------------
__global__ void build_frags(const float* __restrict__ W0,
                            const float* __restrict__ W1,
                            const float* __restrict__ W2,
                            const float* __restrict__ W3,
                            const float* __restrict__ Wf,
                            ushort* __restrict__ stream) {
    const int gid = blockIdx.x * 256 + threadIdx.x;   // 0 .. 28671
    const int f = gid >> 6;
    const int lane = gid & 63;
    const int p16 = lane & 15, g = lane >> 4;
    ushort* dst = stream + (size_t)f * 512 + lane * 8;

    if (f < 16) {                       // L0: W0[f*16+p16][8g+i]
        const float* row = W0 + (size_t)(f * 16 + p16) * 32;
#pragma unroll
        for (int i = 0; i < 8; ++i) dst[i] = f2bf(row[8 * g + i]);
    } else if (f < 32) {
#pragma unroll
        for (int i = 0; i < 8; ++i) dst[i] = 0;
    } else if (f < 416) {
        const int t = f - 32;
        const int h = t >> 7;           // 0,1,2 -> W1,W2,W3
        const int q = (t >> 5) & 3;     // sub-chunk A,B,C,D
        const int ksl = (t >> 3) & 3;
        const int ntl = t & 7;
        const int nt = (q & 1) * 8 + ntl;
        const int ks = (q >> 1) * 4 + ksl;
        const float* W = (h == 0) ? W1 : (h == 1) ? W2 : W3;
        const float* row = W + (size_t)(nt * 16 + p16) * 256;
#pragma unroll
        for (int i = 0; i < 8; ++i) dst[i] = f2bf(row[sigma_k(32 * ks + 8 * g + i)]);
    } else if (f < 424) {               // Wf
        const int ks = f - 416;
        if (p16 < 4) {
            const float* row = Wf + (size_t)p16 * 256;
#pragma unroll
            for (int i = 0; i < 8; ++i) dst[i] = f2bf(row[sigma_k(32 * ks + 8 * g + i)]);
        } else {
#pragma unroll
            for (int i = 0; i < 8; ++i) dst[i] = 0;
        }
    } else {
#pragma unroll
        for (int i = 0; i < 8; ++i) dst[i] = 0;
    }
}

// vol [B][32][32768] f32 -> dst [B*32768][32] f32 (channel-last)
__global__ void vol_chlast(const float* __restrict__ vol, float* __restrict__ dst, int nvox) {
    int v = blockIdx.x * 256 + threadIdx.x;
    if (v >= nvox) return;
    const int b = v >> 15, idx = v & 32767;
    const float* s = vol + (size_t)b * 32 * 32768 + idx;
    float* d = dst + (size_t)v * 32;
#pragma unroll
    for (int c = 0; c < 32; ++c) d[c] = s[(size_t)c * 32768];
}

// ---------------- main fused kernel ----------------
#define MF(a, b, c) __builtin_amdgcn_mfma_f32_16x16x32_bf16((a), (b), (c), 0, 0, 0)

__global__ __launch_bounds__(THREADS, 2)
void siren_pl(const float* __restrict__ points,
              const float* __restrict__ vol,
              const float* __restrict__ b0, const float* __restrict__ b1,
              const float* __restrict__ b2, const float* __restrict__ b3,
              const float* __restrict__ bfin,
              const ushort* __restrict__ Wstream,
              const float* __restrict__ volcl, int use_cl,
              float* __restrict__ out, long long total, int N) {
    __shared__ ushort ring[2][16384];   // 2 x 32KB

    const int tid = (int)threadIdx.x;
    const int w = tid >> 6;             // wave 0..3
    const int lane = tid & 63;
    const int p16 = lane & 15;
    const int g = lane >> 4;

    const long long base = (long long)blockIdx.x * 128;

    auto stage = [&](int c) {
        if (c >= 14) return;
        const ushort* src = Wstream + (size_t)c * 16384;
        ushort* dstbase = &ring[c & 1][0];
#pragma unroll
        for (int q = 0; q < 8; ++q) {
            const int off = (q * 4 + w) * 512;   // elements; wave-uniform
            __builtin_amdgcn_global_load_lds(
                (const __attribute__((address_space(1))) unsigned int*)(src + off + lane * 8),
                (__attribute__((address_space(3))) unsigned int*)(dstbase + off),
                16, 0, 0);
        }
    };
    stage(0);
    stage(1);

    // ---- sample 2 points per lane: channels 8g..8g+7 ----
    bf16x8 af0[2];
    {
#pragma unroll
        for (int ptt = 0; ptt < 2; ++ptt) {
            const long long gidx = base + w * 32 + ptt * 16 + p16;
            const long long gp = gidx < total ? gidx : total - 1;
            const int bi = (int)(gp / N);
            const float* pp = points + gp * 3;
            const float sc = 1.0f / 0.6f;
            const float ix = (pp[0] * sc + 1.0f) * 16.0f - 0.5f;
            const float iy = (pp[1] * sc + 1.0f) * 16.0f - 0.5f;
            const float iz = (pp[2] * sc + 1.0f) * 16.0f - 0.5f;
            const float fx = floorf(ix), fy = floorf(iy), fz = floorf(iz);
            const float wx = ix - fx, wy = iy - fy, wz = iz - fz;
            const int x0 = (int)fminf(fmaxf(fx, 0.0f), 31.0f);
            const int x1 = (int)fminf(fmaxf(fx + 1.0f, 0.0f), 31.0f);
            const int y0 = (int)fminf(fmaxf(fy, 0.0f), 31.0f);
            const int y1 = (int)fminf(fmaxf(fy + 1.0f, 0.0f), 31.0f);
            const int z0 = (int)fminf(fmaxf(fz, 0.0f), 31.0f);
            const int z1 = (int)fminf(fmaxf(fz + 1.0f, 0.0f), 31.0f);
            const int i000 = (z0 * 32 + y0) * 32 + x0, i001 = (z0 * 32 + y0) * 32 + x1;
            const int i010 = (z0 * 32 + y1) * 32 + x0, i011 = (z0 * 32 + y1) * 32 + x1;
            const int i100 = (z1 * 32 + y0) * 32 + x0, i101 = (z1 * 32 + y0) * 32 + x1;
            const int i110 = (z1 * 32 + y1) * 32 + x0, i111 = (z1 * 32 + y1) * 32 + x1;
            const float omx = 1.0f - wx, omy = 1.0f - wy, omz = 1.0f - wz;
            const float w000 = omz * omy * omx, w001 = omz * omy * wx;
            const float w010 = omz * wy * omx,  w011 = omz * wy * wx;
            const float w100 = wz * omy * omx,  w101 = wz * omy * wx;
            const float w110 = wz * wy * omx,   w111 = wz * wy * wx;

            f32x4 a[2];
            if (use_cl) {
                const float* vb = volcl + (size_t)bi * 32768 * 32 + g * 8;
#pragma unroll
                for (int h = 0; h < 2; ++h) {
                    const float* vh = vb + h * 4;
                    a[h]  = w000 * *(const f32x4*)(vh + (size_t)i000 * 32);
                    a[h] += w001 * *(const f32x4*)(vh + (size_t)i001 * 32);
                    a[h] += w010 * *(const f32x4*)(vh + (size_t)i010 * 32);
                    a[h] += w011 * *(const f32x4*)(vh + (size_t)i011 * 32);
                    a[h] += w100 * *(const f32x4*)(vh + (size_t)i100 * 32);
                    a[h] += w101 * *(const f32x4*)(vh + (size_t)i101 * 32);
                    a[h] += w110 * *(const f32x4*)(vh + (size_t)i110 * 32);
                    a[h] += w111 * *(const f32x4*)(vh + (size_t)i111 * 32);
                }
            } else {
                const float* vb = vol + ((size_t)bi * 32 + (size_t)g * 8) * 32768;
#pragma unroll
                for (int c = 0; c < 8; ++c) {
                    const float* vc = vb + (size_t)c * 32768;
                    a[c >> 2][c & 3] =
                        vc[i000] * w000 + vc[i001] * w001 + vc[i010] * w010 + vc[i011] * w011 +
                        vc[i100] * w100 + vc[i101] * w101 + vc[i110] * w110 + vc[i111] * w111;
                }
            }
            union { bf16x8 v; unsigned u[4]; } pk;
            pk.u[0] = cvt_pk_bf16(a[0][0], a[0][1]);
            pk.u[1] = cvt_pk_bf16(a[0][2], a[0][3]);
            pk.u[2] = cvt_pk_bf16(a[1][0], a[1][1]);
            pk.u[3] = cvt_pk_bf16(a[1][2], a[1][3]);
            af0[ptt] = pk.v;
        }
    }

    f32x4 accA[2][8];   // nt 0..7
    f32x4 accB[2][8];   // nt 8..15
    bf16x8 bfr[2][8];   // activations, frag ks=0..7

    auto frag_at = [&](int slot, int idx) -> bf16x8 {
        return *(const bf16x8*)&ring[slot][idx * 512 + lane * 8];
    };
    auto init_half = [&](f32x4 (&A)[2][8], const float* __restrict__ b, int ntbase) {
#pragma unroll
        for (int m = 0; m < 8; ++m) {
            const f32x4 bv = *(const f32x4*)&b[(ntbase + m) * 16 + 4 * g];
            A[0][m] = bv; A[1][m] = bv;
        }
    };
    // pack 8 acc tiles (one nt-half) into bfr[ksbase..ksbase+3]
    auto pack_half = [&](f32x4 (&A)[2][8], int ksbase) {
#pragma unroll
        for (int ptt = 0; ptt < 2; ++ptt)
#pragma unroll
            for (int ks2 = 0; ks2 < 4; ++ks2) {
                union { bf16x8 v; unsigned u[4]; } pk;
#pragma unroll
                for (int j = 0; j < 4; ++j) {
                    const int m = 2 * ks2 + (j >> 1);
                    const int r = 2 * (j & 1);
                    pk.u[j] = cvt_pk_bf16(__sinf(A[ptt][m][r]), __sinf(A[ptt][m][r + 1]));
                }
                bfr[ptt][ksbase + ks2] = pk.v;
            }
    };
    // one 32KB sub-chunk: 32 frags (ksl 0..3 x ntl 0..7) vs bfr[kh*4+ksl]
    auto chunk_mfma = [&](int slot, int kh, f32x4 (&A)[2][8]) {
        __builtin_amdgcn_s_setprio(1);
#pragma unroll
        for (int ksl = 0; ksl < 4; ++ksl) {
            const bf16x8 bA = bfr[0][kh * 4 + ksl];
            const bf16x8 bB = bfr[1][kh * 4 + ksl];
#pragma unroll
            for (int ntl = 0; ntl < 8; ++ntl) {
                const bf16x8 wfr = frag_at(slot, ksl * 8 + ntl);
                A[0][ntl] = MF(wfr, bA, A[0][ntl]);
                A[1][ntl] = MF(wfr, bB, A[1][ntl]);
            }
        }
        __builtin_amdgcn_s_setprio(0);
    };

    init_half(accA, b0, 0);
    init_half(accB, b0, 8);
    __syncthreads();                    // chunks 0,1 staged

    // ---- interval 0: L0 (chunk 0) ----
    __builtin_amdgcn_s_setprio(1);
#pragma unroll
    for (int ntl = 0; ntl < 8; ++ntl) {
        const bf16x8 wl = frag_at(0, ntl);
        const bf16x8 wh = frag_at(0, 8 + ntl);
        accA[0][ntl] = MF(wl, af0[0], accA[0][ntl]);
        accA[1][ntl] = MF(wl, af0[1], accA[1][ntl]);
        accB[0][ntl] = MF(wh, af0[0], accB[0][ntl]);
        accB[1][ntl] = MF(wh, af0[1], accB[1][ntl]);
    }
    __builtin_amdgcn_s_setprio(0);
    __syncthreads(); stage(2);

    // ---- interval 1 (c1 = L1.A) ----
    pack_half(accA, 0); init_half(accA, b1, 0);
    chunk_mfma(1, 0, accA);
    __syncthreads(); stage(3);
    // ---- interval 2 (c2 = L1.B) ----
    pack_half(accB, 4); init_half(accB, b1, 8);
    chunk_mfma(0, 0, accB);
    __syncthreads(); stage(4);
    // ---- interval 3 (c3 = L1.C) ----
    chunk_mfma(1, 1, accA);
    __syncthreads(); stage(5);
    // ---- interval 4 (c4 = L1.D) ----
    pack_half(accA, 0); init_half(accA, b2, 0);
    chunk_mfma(0, 1, accB);
    __syncthreads(); stage(6);
    // ---- interval 5 (c5 = L2.A) ----
    pack_half(accB, 4); init_half(accB, b2, 8);
    chunk_mfma(1, 0, accA);
    __syncthreads(); stage(7);
    // ---- interval 6 (c6 = L2.B) ----
    chunk_mfma(0, 0, accB);
    __syncthreads(); stage(8);
    // ---- interval 7 (c7 = L2.C) ----
    chunk_mfma(1, 1, accA);
    __syncthreads(); stage(9);
    // ---- interval 8 (c8 = L2.D) ----
    pack_half(accA, 0); init_half(accA, b3, 0);
    chunk_mfma(0, 1, accB);
    __syncthreads(); stage(10);
    // ---- interval 9 (c9 = L3.A) ----
    pack_half(accB, 4); init_half(accB, b3, 8);
    chunk_mfma(1, 0, accA);
    __syncthreads(); stage(11);
    // ---- interval 10 (c10 = L3.B) ----
    chunk_mfma(0, 0, accB);
    __syncthreads(); stage(12);
    // ---- interval 11 (c11 = L3.C) ----
    chunk_mfma(1, 1, accA);
    __syncthreads(); stage(13);
    // ---- interval 12 (c12 = L3.D) ----
    pack_half(accA, 0);
    chunk_mfma(0, 1, accB);
    __syncthreads();
    // ---- interval 13 (c13 = Wf) ----
    pack_half(accB, 4);
    {
        f32x4 fo[2] = {{0, 0, 0, 0}, {0, 0, 0, 0}};
#pragma unroll
        for (int ks = 0; ks < 8; ++ks) {
            const bf16x8 wfr = frag_at(1, ks);
            fo[0] = MF(wfr, bfr[0][ks], fo[0]);
            fo[1] = MF(wfr, bfr[1][ks], fo[1]);
        }
        if (g == 0) {
#pragma unroll
            for (int ptt = 0; ptt < 2; ++ptt) {
                const long long oi = base + w * 32 + ptt * 16 + p16;
                if (oi < total) {
                    float4 o;
                    o.x = fast_sigmoid(fo[ptt][0] + bfin[0]);
                    o.y = fast_sigmoid(fo[ptt][1] + bfin[1]);
                    o.z = fast_sigmoid(fo[ptt][2] + bfin[2]);
                    o.w = fo[ptt][3] + bfin[3];
                    *(float4*)(out + oi * 4) = o;
                }
            }
        }
    }
}

extern "C" void kernel_launch(void* const* d_in, const int* in_sizes, int n_in,
                              void* d_out, int out_size, void* d_ws, size_t ws_size,
                              hipStream_t stream) {
    const float* points = (const float*)d_in[0];
    const float* vol    = (const float*)d_in[1];
    const float* W0 = (const float*)d_in[2];
    const float* b0 = (const float*)d_in[3];
    const float* W1 = (const float*)d_in[4];
    const float* b1 = (const float*)d_in[5];
    const float* W2 = (const float*)d_in[6];
    const float* b2 = (const float*)d_in[7];
    const float* W3 = (const float*)d_in[8];
    const float* b3 = (const float*)d_in[9];
    const float* Wf = (const float*)d_in[10];
    const float* bf = (const float*)d_in[11];

    const int B = in_sizes[1] / (32 * 32 * 32 * 32);
    const int N = in_sizes[0] / (3 * B);
    const long long total = (long long)B * N;
    const int tiles = (int)((total + 127) / 128);

    ushort* Wstream = (ushort*)d_ws;
    build_frags<<<112, 256, 0, stream>>>(W0, W1, W2, W3, Wf, Wstream);

    const int use_cl = (ws_size >= (size_t)STREAM_BYTES + (size_t)B * 32768 * 32 * 4) ? 1 : 0;
    float* volcl = (float*)((char*)d_ws + STREAM_BYTES);
    if (use_cl) {
        const int nvox = B * 32768;
        vol_chlast<<<(nvox + 255) / 256, 256, 0, stream>>>(vol, volcl, nvox);
    }

    siren_pl<<<tiles, THREADS, 0, stream>>>(
        points, vol, b0, b1, b2, b3, bf, Wstream, volcl, use_cl,
        (float*)d_out, total, N);
}